// Round 2
// baseline (166.773 us; speedup 1.0000x reference)
//
#include <hip/hip_runtime.h>
#include <math.h>

#define BB 32
#define SS 2048
#define HH 1024
#define RR 64
#define H4 (HH/4)

// flag: 0 = int32, 1 = uint8(bool), 2 = float32
__device__ __forceinline__ bool read_mask(const void* m, int flag, int i) {
    if (flag == 1) return ((const unsigned char*)m)[i] != 0;
    if (flag == 2) return ((const float*)m)[i] != 0.0f;
    return ((const int*)m)[i] != 0;
}

// ---------------- kernel A: answer pooling + mask classify + counter zero ----
// grid = BB+1, block = 256.
//   blocks 0..31 : answer span mean pooling (thread t owns float4 chunk t)
//   block  32    : classify rubric_mask storage dtype, zero per-batch counters
__global__ void pool_classify_k(const float4* __restrict__ seq,
                                const int* __restrict__ aspan,
                                const unsigned char* __restrict__ mask,
                                float4* __restrict__ aemb,
                                int* __restrict__ flag,
                                unsigned int* __restrict__ cnt) {
    int blk = blockIdx.x, t = threadIdx.x;
    if (blk == BB) {
        // classify: uint8 bool => nonzero bytes at i%4==1; f32 => nonzero at
        // i%4==3 only; int32 => nonzero only at i%4==0.
        __shared__ int c1s, c3s;
        if (t == 0) { c1s = 0; c3s = 0; }
        __syncthreads();
        int c1 = 0, c3 = 0;
        for (int i = t; i < BB * RR; i += 256) {
            if (mask[i]) {
                int p = i & 3;
                if (p == 1) c1 = 1;
                else if (p == 3) c3 = 1;
            }
        }
        if (c1) atomicOr(&c1s, 1);
        if (c3) atomicOr(&c3s, 1);
        __syncthreads();
        if (t == 0) *flag = c1s ? 1 : (c3s ? 2 : 0);
        if (t < BB) cnt[t] = 0u;   // zero completion counters every launch
        return;
    }
    int b = blk;
    int s0 = aspan[2 * b], s1 = aspan[2 * b + 1];
    int len = s1 - s0; if (len < 1) len = 1;
    float4 acc = make_float4(0.f, 0.f, 0.f, 0.f);
    const float4* base = seq + (size_t)b * SS * H4 + t;
    for (int s = s0; s < s1; ++s) {
        float4 x = base[(size_t)s * H4];
        acc.x += x.x; acc.y += x.y; acc.z += x.z; acc.w += x.w;
    }
    float inv = 1.0f / (float)len;
    acc.x *= inv; acc.y *= inv; acc.z *= inv; acc.w *= inv;
    aemb[b * H4 + t] = acc;
}

// ---------------- kernel B: v[b,h] = sum_k W[h,k] * a[b,k] ----------------
// grid = H (one block per W row), block = 256 (float4 chunk per thread).
__global__ void bilinear_matvec_k(const float4* __restrict__ Wm,
                                  const float4* __restrict__ aemb,
                                  float* __restrict__ v) {
    int h = blockIdx.x, t = threadIdx.x;
    float4 w = Wm[(size_t)h * H4 + t];
    __shared__ float red[4][BB];
    int wave = t >> 6, lane = t & 63;
    for (int b = 0; b < BB; ++b) {
        float4 a = aemb[b * H4 + t];
        float p = w.x * a.x + w.y * a.y + w.z * a.z + w.w * a.w;
        for (int off = 32; off; off >>= 1) p += __shfl_down(p, off);
        if (lane == 0) red[wave][b] = p;
    }
    __syncthreads();
    if (t < BB) {
        float s = red[0][t] + red[1][t] + red[2][t] + red[3][t];
        v[t * HH + h] = s;   // v[b=t][h]
    }
}

// ---------------- kernel C: rubric scores + fused softmax ----------------
// grid = B*R, block = 256.
// scores[b,r] = (1/len) * sum_{s in span} seq[b,s].v[b] + bias, or -inf.
// The 64th block to finish for batch b runs the softmax (threadfence-
// reduction pattern with agent-scope atomics for cross-XCD visibility).
__global__ void rubric_scores_softmax_k(const float4* __restrict__ seq,
                                        const float4* __restrict__ v4,
                                        const int* __restrict__ rspan,
                                        const void* __restrict__ mask,
                                        const int* __restrict__ flagp,
                                        const float* __restrict__ bias,
                                        float* __restrict__ scores,
                                        unsigned int* __restrict__ cnt,
                                        float* __restrict__ out) {
    int blk = blockIdx.x;
    int b = blk >> 6;          // / RR
    int r = blk & (RR - 1);
    int t = threadIdx.x;
    int idx = b * RR + r;
    int flag = *flagp;
    bool mk = read_mask(mask, flag, idx);

    float p = 0.f;
    int len = 1;
    if (mk) {
        int s0 = rspan[idx * 2], s1 = rspan[idx * 2 + 1];
        len = s1 - s0; if (len < 1) len = 1;
        float4 vv = v4[b * H4 + t];
        const float4* base = seq + (size_t)b * SS * H4 + t;
        for (int s = s0; s < s1; ++s) {
            float4 x = base[(size_t)s * H4];
            p += x.x * vv.x + x.y * vv.y + x.z * vv.z + x.w * vv.w;
        }
    }
    __shared__ float red[4];
    __shared__ int lastB;
    int wave = t >> 6, lane = t & 63;
    for (int off = 32; off; off >>= 1) p += __shfl_down(p, off);
    if (lane == 0) red[wave] = p;
    __syncthreads();
    if (t == 0) {
        float s = red[0] + red[1] + red[2] + red[3];
        float val = mk ? (s / (float)len + bias[0]) : -INFINITY;
        __hip_atomic_store(&scores[idx], val, __ATOMIC_RELEASE,
                           __HIP_MEMORY_SCOPE_AGENT);
        unsigned old = __hip_atomic_fetch_add(&cnt[b], 1u, __ATOMIC_ACQ_REL,
                                              __HIP_MEMORY_SCOPE_AGENT);
        lastB = (old == RR - 1);
    }
    __syncthreads();
    if (lastB && t < RR) {
        float x = __hip_atomic_load(&scores[b * RR + t], __ATOMIC_ACQUIRE,
                                    __HIP_MEMORY_SCOPE_AGENT);
        float m = x;
        for (int off = 32; off; off >>= 1) m = fmaxf(m, __shfl_xor(m, off));
        float e = expf(x - m);              // -inf lanes -> 0
        float s = e;
        for (int off = 32; off; off >>= 1) s += __shfl_xor(s, off);
        out[b * RR + t] = e / s;
    }
}

extern "C" void kernel_launch(void* const* d_in, const int* in_sizes, int n_in,
                              void* d_out, int out_size, void* d_ws, size_t ws_size,
                              hipStream_t stream) {
    const float* seq  = (const float*)d_in[0];
    const float* Wm   = (const float*)d_in[1];
    const float* bias = (const float*)d_in[2];
    const int*   rspan = (const int*)d_in[3];
    const int*   aspan = (const int*)d_in[4];
    const void*  mask  = d_in[5];

    char* ws = (char*)d_ws;
    int*          flag   = (int*)ws;                       // 4 B (pad to 256)
    float*        aemb   = (float*)(ws + 256);             // 32*1024 f
    float*        v      = aemb + BB * HH;                 // 32*1024 f
    float*        scores = v + BB * HH;                    // 2048 f
    unsigned int* cnt    = (unsigned int*)(scores + BB * RR);  // 32 u32

    pool_classify_k<<<BB + 1, 256, 0, stream>>>((const float4*)seq, aspan,
                                                (const unsigned char*)mask,
                                                (float4*)aemb, flag, cnt);
    bilinear_matvec_k<<<HH, 256, 0, stream>>>((const float4*)Wm,
                                              (const float4*)aemb, v);
    rubric_scores_softmax_k<<<BB * RR, 256, 0, stream>>>(
        (const float4*)seq, (const float4*)v, rspan, mask, flag, bias,
        scores, cnt, (float*)d_out);
}

// Round 3
// 52.582 us; speedup vs baseline: 3.1717x; 3.1717x over previous
//
#include <hip/hip_runtime.h>
#include <math.h>

#define BB 32
#define SS 2048
#define HH 1024
#define RR 64
#define H4 (HH/4)

// flag: 0 = int32, 1 = uint8(bool), 2 = float32
__device__ __forceinline__ bool read_mask(const void* m, int flag, int i) {
    if (flag == 1) return ((const unsigned char*)m)[i] != 0;
    if (flag == 2) return ((const float*)m)[i] != 0.0f;
    return ((const int*)m)[i] != 0;
}

// ---------------- kernel A: answer pooling + mask classify + counter zero ----
// grid = BB+1, block = 256.
//   blocks 0..31 : answer span mean pooling (thread t owns float4 chunk t)
//   block  32    : classify rubric_mask storage dtype, zero per-batch counters
__global__ void pool_classify_k(const float4* __restrict__ seq,
                                const int* __restrict__ aspan,
                                const unsigned char* __restrict__ mask,
                                float4* __restrict__ aemb,
                                int* __restrict__ flag,
                                unsigned int* __restrict__ cnt) {
    int blk = blockIdx.x, t = threadIdx.x;
    if (blk == BB) {
        // uint8 bool => nonzero bytes at i%4==1; f32 => nonzero only at i%4==3;
        // int32 => nonzero only at i%4==0.
        __shared__ int c1s, c3s;
        if (t == 0) { c1s = 0; c3s = 0; }
        __syncthreads();
        int c1 = 0, c3 = 0;
        for (int i = t; i < BB * RR; i += 256) {
            if (mask[i]) {
                int p = i & 3;
                if (p == 1) c1 = 1;
                else if (p == 3) c3 = 1;
            }
        }
        if (c1) atomicOr(&c1s, 1);
        if (c3) atomicOr(&c3s, 1);
        __syncthreads();
        if (t == 0) *flag = c1s ? 1 : (c3s ? 2 : 0);
        if (t < BB) cnt[t] = 0u;   // re-zero completion counters every launch
        return;
    }
    int b = blk;
    int s0 = aspan[2 * b], s1 = aspan[2 * b + 1];
    int len = s1 - s0; if (len < 1) len = 1;
    float4 acc = make_float4(0.f, 0.f, 0.f, 0.f);
    const float4* base = seq + (size_t)b * SS * H4 + t;
    for (int s = s0; s < s1; ++s) {
        float4 x = base[(size_t)s * H4];
        acc.x += x.x; acc.y += x.y; acc.z += x.z; acc.w += x.w;
    }
    float inv = 1.0f / (float)len;
    acc.x *= inv; acc.y *= inv; acc.z *= inv; acc.w *= inv;
    aemb[b * H4 + t] = acc;
}

// ---------------- kernel B: v[b,h] = sum_k W[h,k] * a[b,k] ----------------
// grid = H (one block per W row), block = 256 (float4 chunk per thread).
__global__ void bilinear_matvec_k(const float4* __restrict__ Wm,
                                  const float4* __restrict__ aemb,
                                  float* __restrict__ v) {
    int h = blockIdx.x, t = threadIdx.x;
    float4 w = Wm[(size_t)h * H4 + t];
    __shared__ float red[4][BB];
    int wave = t >> 6, lane = t & 63;
    for (int b = 0; b < BB; ++b) {
        float4 a = aemb[b * H4 + t];
        float p = w.x * a.x + w.y * a.y + w.z * a.z + w.w * a.w;
        for (int off = 32; off; off >>= 1) p += __shfl_down(p, off);
        if (lane == 0) red[wave][b] = p;
    }
    __syncthreads();
    if (t < BB) {
        float s = red[0][t] + red[1][t] + red[2][t] + red[3][t];
        v[t * HH + h] = s;   // v[b=t][h]
    }
}

// ---------------- kernel C: rubric scores + fused softmax ----------------
// grid = B*R, block = 256. blk = r*32 + b so batch b's 64 blocks all land on
// XCD b%8 (L2 reuse of span rows).
// Fence-free cross-XCD handoff: relaxed agent-scope (sc1, L2-bypassing)
// stores/loads for the score values, ordered by s_waitcnt vmcnt(0) before the
// relaxed device-scope counter bump. NO acquire/release -> no L2
// writeback/invalidate walks (the R2 disaster: ~0.1ms of serialized cache
// maintenance from per-block acq_rel fences).
__global__ void rubric_scores_softmax_k(const float4* __restrict__ seq,
                                        const float4* __restrict__ v4,
                                        const int* __restrict__ rspan,
                                        const void* __restrict__ mask,
                                        const int* __restrict__ flagp,
                                        const float* __restrict__ bias,
                                        float* __restrict__ scores,
                                        unsigned int* __restrict__ cnt,
                                        float* __restrict__ out) {
    int blk = blockIdx.x;
    int b = blk & (BB - 1);
    int r = blk >> 5;
    int t = threadIdx.x;
    int idx = b * RR + r;
    int flag = *flagp;
    bool mk = read_mask(mask, flag, idx);

    float p = 0.f;
    int len = 1;
    if (mk) {
        int s0 = rspan[idx * 2], s1 = rspan[idx * 2 + 1];
        len = s1 - s0; if (len < 1) len = 1;
        float4 vv = v4[b * H4 + t];
        const float4* base = seq + (size_t)b * SS * H4 + t;
        for (int s = s0; s < s1; ++s) {
            float4 x = base[(size_t)s * H4];
            p += x.x * vv.x + x.y * vv.y + x.z * vv.z + x.w * vv.w;
        }
    }
    __shared__ float red[4];
    __shared__ int lastB;
    int wave = t >> 6, lane = t & 63;
    for (int off = 32; off; off >>= 1) p += __shfl_down(p, off);
    if (lane == 0) red[wave] = p;
    __syncthreads();
    if (t == 0) {
        float s = red[0] + red[1] + red[2] + red[3];
        float val = mk ? (s / (float)len + bias[0]) : -INFINITY;
        __hip_atomic_store(&scores[idx], val, __ATOMIC_RELAXED,
                           __HIP_MEMORY_SCOPE_AGENT);
        asm volatile("s_waitcnt vmcnt(0)" ::: "memory");  // score visible @ L3
        unsigned old = atomicAdd(&cnt[b], 1u);            // relaxed, device
        asm volatile("" ::: "memory");
        lastB = (old == RR - 1);
    }
    __syncthreads();
    if (lastB && t < RR) {
        float x = __hip_atomic_load(&scores[b * RR + t], __ATOMIC_RELAXED,
                                    __HIP_MEMORY_SCOPE_AGENT);
        float m = x;
        for (int off = 32; off; off >>= 1) m = fmaxf(m, __shfl_xor(m, off));
        float e = expf(x - m);              // -inf lanes -> 0
        float s = e;
        for (int off = 32; off; off >>= 1) s += __shfl_xor(s, off);
        out[b * RR + t] = e / s;
    }
}

extern "C" void kernel_launch(void* const* d_in, const int* in_sizes, int n_in,
                              void* d_out, int out_size, void* d_ws, size_t ws_size,
                              hipStream_t stream) {
    const float* seq  = (const float*)d_in[0];
    const float* Wm   = (const float*)d_in[1];
    const float* bias = (const float*)d_in[2];
    const int*   rspan = (const int*)d_in[3];
    const int*   aspan = (const int*)d_in[4];
    const void*  mask  = d_in[5];

    char* ws = (char*)d_ws;
    int*          flag   = (int*)ws;                       // 4 B (pad to 256)
    float*        aemb   = (float*)(ws + 256);             // 32*1024 f
    float*        v      = aemb + BB * HH;                 // 32*1024 f
    float*        scores = v + BB * HH;                    // 2048 f
    unsigned int* cnt    = (unsigned int*)(scores + BB * RR);  // 32 u32

    pool_classify_k<<<BB + 1, 256, 0, stream>>>((const float4*)seq, aspan,
                                                (const unsigned char*)mask,
                                                (float4*)aemb, flag, cnt);
    bilinear_matvec_k<<<HH, 256, 0, stream>>>((const float4*)Wm,
                                              (const float4*)aemb, v);
    rubric_scores_softmax_k<<<BB * RR, 256, 0, stream>>>(
        (const float4*)seq, (const float4*)v, rspan, mask, flag, bias,
        scores, cnt, (float*)d_out);
}

// Round 4
// 41.845 us; speedup vs baseline: 3.9854x; 1.2566x over previous
//
#include <hip/hip_runtime.h>
#include <math.h>

#define BB 32
#define SS 2048
#define HH 1024
#define RR 64
#define H4 (HH/4)

// flag: 0 = int32, 1 = uint8(bool), 2 = float32
__device__ __forceinline__ bool read_mask(const void* m, int flag, int i) {
    if (flag == 1) return ((const unsigned char*)m)[i] != 0;
    if (flag == 2) return ((const float*)m)[i] != 0.0f;
    return ((const int*)m)[i] != 0;
}

__device__ __forceinline__ float dot4(float4 a, float4 b) {
    return a.x * b.x + a.y * b.y + a.z * b.z + a.w * b.w;
}

// ---------------- K1: answer pool + bilinear matvec (fused) ----------------
// grid = 512 (b = blk>>4, hg = blk&15), block = 256.
// Each block recomputes a[b] (answer rows are tiny & L2/L3-resident), stashes
// it in LDS, then computes v[b, hg*64 .. hg*64+64) with coalesced W reads.
// Block 0 additionally classifies the rubric_mask storage dtype and zeroes
// the per-batch completion counters used by K2's fused softmax.
__global__ void pool_matvec_k(const float4* __restrict__ seq,
                              const float4* __restrict__ W4,
                              const int* __restrict__ aspan,
                              const unsigned char* __restrict__ mask,
                              float* __restrict__ v,
                              int* __restrict__ flag,
                              unsigned int* __restrict__ cnt) {
    int blk = blockIdx.x, t = threadIdx.x;
    int b = blk >> 4, hg = blk & 15;

    // --- answer span mean pooling (thread t owns float4 chunk t of H) ---
    int s0 = aspan[2 * b], s1 = aspan[2 * b + 1];
    int len = s1 - s0; if (len < 1) len = 1;
    float4 acc = make_float4(0.f, 0.f, 0.f, 0.f);
    const float4* base = seq + (size_t)b * SS * H4 + t;
    for (int s = s0; s < s1; ++s) {
        float4 x = base[(size_t)s * H4];
        acc.x += x.x; acc.y += x.y; acc.z += x.z; acc.w += x.w;
    }
    float inv = 1.0f / (float)len;
    acc.x *= inv; acc.y *= inv; acc.z *= inv; acc.w *= inv;

    __shared__ float4 aS[256];
    aS[t] = acc;
    __syncthreads();

    // --- matvec: wave w handles rows hg*64 + w*16 .. +16 ---
    int wave = t >> 6, lane = t & 63;
    // lane's a-slice: elements (k*64+lane)*4 .. +4, k = 0..3  (8-way LDS, once)
    float4 al0 = aS[0 * 64 + lane];
    float4 al1 = aS[1 * 64 + lane];
    float4 al2 = aS[2 * 64 + lane];
    float4 al3 = aS[3 * 64 + lane];
    int hbase = hg * 64 + wave * 16;
    for (int r = 0; r < 16; ++r) {
        int h = hbase + r;
        const float4* Wrow = W4 + (size_t)h * H4;
        // coalesced: consecutive lanes -> consecutive float4s
        float p = dot4(Wrow[0 * 64 + lane], al0)
                + dot4(Wrow[1 * 64 + lane], al1)
                + dot4(Wrow[2 * 64 + lane], al2)
                + dot4(Wrow[3 * 64 + lane], al3);
        for (int off = 32; off; off >>= 1) p += __shfl_down(p, off);
        if (lane == 0) v[b * HH + h] = p;
    }

    // --- block 0 side duties: mask dtype classify + counter zero ---
    if (blk == 0) {
        __shared__ int c1s, c3s;
        if (t == 0) { c1s = 0; c3s = 0; }
        __syncthreads();
        int c1 = 0, c3 = 0;
        for (int i = t; i < BB * RR; i += 256) {
            if (mask[i]) {
                int p = i & 3;
                if (p == 1) c1 = 1;
                else if (p == 3) c3 = 1;
            }
        }
        if (c1) atomicOr(&c1s, 1);
        if (c3) atomicOr(&c3s, 1);
        __syncthreads();
        if (t == 0) *flag = c1s ? 1 : (c3s ? 2 : 0);
        if (t < BB) cnt[t] = 0u;    // re-zero every launch (graph replay safe)
    }
}

// ---------------- K2: rubric scores + fused softmax ----------------
// grid = B*R, block = 256. blk = r*32 + b so batch b's 64 blocks land on XCD
// b%8 (span-row L2 reuse). Fence-free cross-XCD handoff (R3-proven): relaxed
// agent-scope (sc1) score stores/loads ordered by s_waitcnt vmcnt(0) before a
// relaxed device-scope counter bump. No acquire/release -> no L2 cache walks.
__global__ void rubric_scores_softmax_k(const float4* __restrict__ seq,
                                        const float4* __restrict__ v4,
                                        const int* __restrict__ rspan,
                                        const void* __restrict__ mask,
                                        const int* __restrict__ flagp,
                                        const float* __restrict__ bias,
                                        float* __restrict__ scores,
                                        unsigned int* __restrict__ cnt,
                                        float* __restrict__ out) {
    int blk = blockIdx.x;
    int b = blk & (BB - 1);
    int r = blk >> 5;
    int t = threadIdx.x;
    int idx = b * RR + r;
    int flag = *flagp;
    bool mk = read_mask(mask, flag, idx);

    float p = 0.f;
    int len = 1;
    if (mk) {
        int s0 = rspan[idx * 2], s1 = rspan[idx * 2 + 1];
        len = s1 - s0; if (len < 1) len = 1;
        float4 vv = v4[b * H4 + t];
        const float4* base = seq + (size_t)b * SS * H4 + t;
        for (int s = s0; s < s1; ++s) {
            float4 x = base[(size_t)s * H4];
            p += x.x * vv.x + x.y * vv.y + x.z * vv.z + x.w * vv.w;
        }
    }
    __shared__ float red[4];
    __shared__ int lastB;
    int wave = t >> 6, lane = t & 63;
    for (int off = 32; off; off >>= 1) p += __shfl_down(p, off);
    if (lane == 0) red[wave] = p;
    __syncthreads();
    if (t == 0) {
        float s = red[0] + red[1] + red[2] + red[3];
        float val = mk ? (s / (float)len + bias[0]) : -INFINITY;
        __hip_atomic_store(&scores[idx], val, __ATOMIC_RELAXED,
                           __HIP_MEMORY_SCOPE_AGENT);
        asm volatile("s_waitcnt vmcnt(0)" ::: "memory");  // score @ coherence pt
        unsigned old = atomicAdd(&cnt[b], 1u);            // relaxed, device
        asm volatile("" ::: "memory");
        lastB = (old == RR - 1);
    }
    __syncthreads();
    if (lastB && t < RR) {
        float x = __hip_atomic_load(&scores[b * RR + t], __ATOMIC_RELAXED,
                                    __HIP_MEMORY_SCOPE_AGENT);
        float m = x;
        for (int off = 32; off; off >>= 1) m = fmaxf(m, __shfl_xor(m, off));
        float e = expf(x - m);              // -inf lanes -> 0
        float s = e;
        for (int off = 32; off; off >>= 1) s += __shfl_xor(s, off);
        out[b * RR + t] = e / s;
    }
}

extern "C" void kernel_launch(void* const* d_in, const int* in_sizes, int n_in,
                              void* d_out, int out_size, void* d_ws, size_t ws_size,
                              hipStream_t stream) {
    const float* seq  = (const float*)d_in[0];
    const float* Wm   = (const float*)d_in[1];
    const float* bias = (const float*)d_in[2];
    const int*   rspan = (const int*)d_in[3];
    const int*   aspan = (const int*)d_in[4];
    const void*  mask  = d_in[5];

    char* ws = (char*)d_ws;
    int*          flag   = (int*)ws;                        // @0
    unsigned int* cnt    = (unsigned int*)(ws + 256);       // 32 u32
    float*        scores = (float*)(ws + 4096);             // 2048 f
    float*        v      = (float*)(ws + 16384);            // 32*1024 f

    pool_matvec_k<<<BB * 16, 256, 0, stream>>>(
        (const float4*)seq, (const float4*)Wm, aspan,
        (const unsigned char*)mask, v, flag, cnt);
    rubric_scores_softmax_k<<<BB * RR, 256, 0, stream>>>(
        (const float4*)seq, (const float4*)v, rspan, mask, flag, bias,
        scores, cnt, (float*)d_out);
}